// Round 7
// baseline (56.426 us; speedup 1.0000x reference)
//
#include <hip/hip_runtime.h>
#include <math.h>

// Problem constants (from reference)
#define BB 2
#define CC 8
#define DD 64
#define HH 160
#define WW 160
#define SS (DD*HH*WW)            // 1,638,400 voxels per sample per channel
#define NVOX (BB*SS)             // 3,276,800 total voxels
#define THREADS 256
#define GPT 2                    // float4 groups per thread
#define BLOCKS_PER_SAMPLE (SS/(THREADS*4*GPT))   // 800
#define NBLOCKS (BB*BLOCKS_PER_SAMPLE)           // 1600

#define L2E 1.4426950408889634f
#define LN2 0.6931471805599453f

typedef float f32x4 __attribute__((ext_vector_type(4)));

// Kernel 1: read target (one-hot, nontemporal), write packed 4-bit labels
// (ushort per float4-group), per-block count partials + per-block presence
// bitmask pb[block] (plain stores, no contention).
__global__ __launch_bounds__(THREADS)
void pass_label(const f32x4* __restrict__ tgt,
                unsigned short* __restrict__ lab16,
                unsigned int* __restrict__ cnt_part,
                unsigned int* __restrict__ pb) {
    __shared__ unsigned int scnt[CC];
    const int tid = threadIdx.x;
    if (tid < CC) scnt[tid] = 0u;
    __syncthreads();

    const int b   = blockIdx.x / BLOCKS_PER_SAMPLE;
    const int blk = blockIdx.x % BLOCKS_PER_SAMPLE;
    const int S4  = SS / 4;
    const f32x4* base = tgt + (size_t)b * CC * S4;
    unsigned short* lab = lab16 + (size_t)b * S4;

    for (int it = 0; it < GPT; ++it) {
        const int g = blk * (THREADS * GPT) + it * THREADS + tid;
        f32x4 v[CC];
        #pragma unroll
        for (int c = 0; c < CC; ++c) v[c] = __builtin_nontemporal_load(base + (size_t)c * S4 + g);

        int l0 = 0, l1 = 0, l2 = 0, l3 = 0;
        #pragma unroll
        for (int c = 1; c < CC; ++c) {
            if (v[c][0] > 0.5f) l0 = c;
            if (v[c][1] > 0.5f) l1 = c;
            if (v[c][2] > 0.5f) l2 = c;
            if (v[c][3] > 0.5f) l3 = c;
        }
        lab[g] = (unsigned short)(l0 | (l1 << 4) | (l2 << 8) | (l3 << 12));
        atomicAdd(&scnt[l0], 1u);   // LDS atomics: no cross-block contention
        atomicAdd(&scnt[l1], 1u);
        atomicAdd(&scnt[l2], 1u);
        atomicAdd(&scnt[l3], 1u);
    }
    __syncthreads();
    if (tid < CC) cnt_part[tid * NBLOCKS + blockIdx.x] = scnt[tid];
    if (tid == 0) {
        unsigned int mask = 0;
        #pragma unroll
        for (int c = 0; c < CC; ++c) mask |= (scnt[c] > 0u) ? (1u << c) : 0u;
        pb[blockIdx.x] = mask;
    }
}

// Kernel 2: cheap prologue ORs pb[] (6.4 KB, L2) -> presence/pad in-register,
// hidden under the first HBM loads; main loop reads net_output (nontemporal)
// + packed labels; per-block partials for seg[8], inter[8], ce.
__global__ __launch_bounds__(THREADS)
void pass_main(const f32x4* __restrict__ net,
               const unsigned short* __restrict__ lab16,
               const unsigned int* __restrict__ pb,
               float* __restrict__ part) {
    __shared__ unsigned int smask[2];
    __shared__ float s_red[2 * CC + 1];   // seg[8], inter[8], ce

    const int tid = threadIdx.x;
    const int b   = blockIdx.x / BLOCKS_PER_SAMPLE;
    const int blk = blockIdx.x % BLOCKS_PER_SAMPLE;

    if (tid < 2) smask[tid] = 0u;
    if (tid < 2 * CC + 1) s_red[tid] = 0.0f;
    __syncthreads();

    const int S4 = SS / 4;
    const f32x4* base = net + (size_t)b * CC * S4;
    const unsigned short* lab = lab16 + (size_t)b * S4;

    // issue first-iteration HBM loads BEFORE the prologue reads
    const int g0 = blk * (THREADS * GPT) + tid;
    f32x4 v0[CC];
    #pragma unroll
    for (int c = 0; c < CC; ++c) v0[c] = __builtin_nontemporal_load(base + (size_t)c * S4 + g0);
    const unsigned int Lp0 = lab[g0];

    // presence OR-reduce (L2-resident; coherent via kernel boundary)
    {
        unsigned int om0 = 0, om1 = 0;
        for (int i = tid; i < NBLOCKS; i += THREADS) {
            const unsigned int m = pb[i];
            if (i < BLOCKS_PER_SAMPLE) om0 |= m; else om1 |= m;
        }
        if (om0) atomicOr(&smask[0], om0);
        if (om1) atomicOr(&smask[1], om1);
    }
    __syncthreads();

    const unsigned int mask0 = smask[0], mask1 = smask[1];
    const int n0 = __popc(mask0), n1 = __popc(mask1);
    const int maxn = n0 > n1 ? n0 : n1;
    const float padf = (float)(maxn - ((b == 0) ? n0 : n1));
    const unsigned int maskb = (b == 0) ? mask0 : mask1;
    float ab[CC], bias[CC];
    #pragma unroll
    for (int c = 0; c < CC; ++c) {
        ab[c]   = ((maskb >> c) & 1u) ? 0.0f : 1.0f;
        bias[c] = -2048.0f * ab[c];
    }

    float segA[CC];
    float intA[CC];
    #pragma unroll
    for (int c = 0; c < CC; ++c) { segA[c] = 0.0f; intA[c] = 0.0f; }
    float ceA = 0.0f;

    #pragma unroll
    for (int it = 0; it < GPT; ++it) {
        f32x4 v[CC];
        unsigned int Lp;
        if (it == 0) {
            #pragma unroll
            for (int c = 0; c < CC; ++c) v[c] = v0[c];
            Lp = Lp0;
        } else {
            const int g = blk * (THREADS * GPT) + it * THREADS + tid;
            #pragma unroll
            for (int c = 0; c < CC; ++c) v[c] = __builtin_nontemporal_load(base + (size_t)c * S4 + g);
            Lp = lab[g];
        }

        #pragma unroll
        for (int j = 0; j < 4; ++j) {
            const int lab_j = (Lp >> (4 * j)) & 0xF;
            float m[CC];
            m[0] = v[0][j];
            // absent-foreground fold, explicit pairwise tree (no fast-math reassoc)
            float f1 = ab[1] * v[1][j];
            float f2 = ab[2] * v[2][j];
            float f3 = ab[3] * v[3][j];
            float f4 = ab[4] * v[4][j];
            float f5 = ab[5] * v[5][j];
            float f6 = ab[6] * v[6][j];
            float f7 = ab[7] * v[7][j];
            #pragma unroll
            for (int c = 1; c < CC; ++c) m[c] = v[c][j];
            m[0] += ((f1 + f2) + (f3 + f4)) + ((f5 + f6) + f7);

            // e[c] = present ? exp(m[c]) : 0   (bias -2048 underflows exp2 to 0)
            float e[CC];
            #pragma unroll
            for (int c = 0; c < CC; ++c)
                e[c] = __builtin_amdgcn_exp2f(fmaf(m[c], L2E, bias[c]));
            const float sp = ((e[0] + e[1]) + (e[2] + e[3])) + ((e[4] + e[5]) + (e[6] + e[7]));
            const float se = sp + padf;         // zero-logit padding: exp(0)*pad
            const float lse = LN2 * __builtin_amdgcn_logf(se);

            float inv = __builtin_amdgcn_rcpf(sp);
            inv = inv * (2.0f - sp * inv);      // 1 Newton step

            float mlab = 0.0f;
            #pragma unroll
            for (int c = 0; c < CC; ++c) {
                const float p = e[c] * inv;
                segA[c] += p;
                const bool isl = (lab_j == c);
                intA[c] += isl ? p : 0.0f;
                mlab     = isl ? m[c] : mlab;
            }
            ceA += lse - mlab;
        }
    }

    // wave-level reduction (64 lanes) then LDS accumulation
    #pragma unroll
    for (int off = 32; off > 0; off >>= 1) {
        #pragma unroll
        for (int c = 0; c < CC; ++c) {
            segA[c] += __shfl_down(segA[c], off, 64);
            intA[c] += __shfl_down(intA[c], off, 64);
        }
        ceA += __shfl_down(ceA, off, 64);
    }
    if ((tid & 63) == 0) {
        #pragma unroll
        for (int c = 0; c < CC; ++c) {
            atomicAdd(&s_red[c],      segA[c]);
            atomicAdd(&s_red[CC + c], intA[c]);
        }
        atomicAdd(&s_red[2 * CC], ceA);
    }
    __syncthreads();
    if (tid < 2 * CC + 1) part[tid * NBLOCKS + blockIdx.x] = s_red[tid];
}

// Kernel 3: reduce per-block fp partials + count partials, write scalar loss.
__global__ __launch_bounds__(512)
void finalize(const unsigned int* __restrict__ cnt_part,
              const float* __restrict__ part,
              float* __restrict__ out) {
    __shared__ float sred[2 * CC + 1][2];
    __shared__ unsigned int sc[2 * CC];
    const int tid = threadIdx.x;
    const int w = tid >> 6, lane = tid & 63;

    // fp partials: wave w handles columns q = w, w+8, w+16
    for (int q = w; q < 2 * CC + 1; q += 8) {
        float a0 = 0.0f, a1 = 0.0f;
        const float* col = part + q * NBLOCKS;
        #pragma unroll
        for (int k = 0; k < NBLOCKS / 64; ++k) {
            const int idx = lane + (k << 6);
            const float v = col[idx];
            if (idx < BLOCKS_PER_SAMPLE) a0 += v; else a1 += v;
        }
        #pragma unroll
        for (int off = 32; off > 0; off >>= 1) {
            a0 += __shfl_down(a0, off, 64);
            a1 += __shfl_down(a1, off, 64);
        }
        if (lane == 0) { sred[q][0] = a0; sred[q][1] = a1; }
    }
    // count partials: wave w handles channel w
    {
        unsigned int a0 = 0, a1 = 0;
        const unsigned int* col = cnt_part + w * NBLOCKS;
        #pragma unroll
        for (int k = 0; k < NBLOCKS / 64; ++k) {
            const int idx = lane + (k << 6);
            const unsigned int v = col[idx];
            if (idx < BLOCKS_PER_SAMPLE) a0 += v; else a1 += v;
        }
        #pragma unroll
        for (int off = 32; off > 0; off >>= 1) {
            a0 += __shfl_down(a0, off, 64);
            a1 += __shfl_down(a1, off, 64);
        }
        if (lane == 0) { sc[w] = a0; sc[CC + w] = a1; }
    }
    __syncthreads();
    if (tid == 0) {
        const float ce = (sred[2 * CC][0] + sred[2 * CC][1]) / (float)NVOX;
        float dc = 0.0f;
        for (int b = 0; b < BB; ++b) {
            int nb = 0;
            float acc = 0.0f;
            for (int c = 0; c < CC; ++c) {
                const unsigned int cnt = sc[b * CC + c];
                if (cnt > 0u) {
                    ++nb;
                    const float R = (float)cnt;
                    const float Sg = sred[c][b];
                    const float I  = sred[CC + c][b];
                    acc += 2.0f * I / (R + Sg + 1e-5f);
                }
            }
            dc += 1.0f - acc / (float)nb;
        }
        dc /= (float)BB;
        out[0] = 0.5f * ce + 0.5f * dc;
    }
}

extern "C" void kernel_launch(void* const* d_in, const int* in_sizes, int n_in,
                              void* d_out, int out_size, void* d_ws, size_t ws_size,
                              hipStream_t stream) {
    const f32x4* net = (const f32x4*)d_in[0];
    const f32x4* tgt = (const f32x4*)d_in[1];
    float* out = (float*)d_out;

    // workspace layout (every slot fully rewritten by its producer each call)
    unsigned int*   cnt_part = (unsigned int*)d_ws;                      // 8*1600 u32  @0       (51200 B)
    unsigned int*   pb       = (unsigned int*)((char*)d_ws + 51200);     // 1600 u32    @51200   (6400 B)
    float*          part     = (float*)((char*)d_ws + 57600);            // 17*1600 f32 @57600   (108800 B)
    unsigned short* lab16    = (unsigned short*)((char*)d_ws + 166400);  // NVOX/4 ushort (1.64 MB)

    pass_label<<<NBLOCKS, THREADS, 0, stream>>>(tgt, lab16, cnt_part, pb);
    pass_main<<<NBLOCKS, THREADS, 0, stream>>>(net, lab16, pb, part);
    finalize<<<1, 512, 0, stream>>>(cnt_part, part, out);
}

// Round 8
// 46.149 us; speedup vs baseline: 1.2227x; 1.2227x over previous
//
#include <hip/hip_runtime.h>
#include <math.h>

// Problem constants (from reference)
#define BB 2
#define CC 8
#define DD 64
#define HH 160
#define WW 160
#define SS (DD*HH*WW)            // 1,638,400 voxels per sample per channel
#define NVOX (BB*SS)             // 3,276,800 total voxels
#define THREADS 256
#define GPT 2                    // float4 groups per thread
#define BLOCKS_PER_SAMPLE (SS/(THREADS*4*GPT))   // 800
#define NBLOCKS (BB*BLOCKS_PER_SAMPLE)           // 1600

#define L2E 1.4426950408889634f
#define LN2 0.6931471805599453f

typedef float f32x4 __attribute__((ext_vector_type(4)));

// Kernel 1: read target (one-hot, nontemporal), write packed 4-bit labels
// (ushort per float4-group), per-block count partials + per-block presence
// bitmask pb[block] (plain stores, no contention).
__global__ __launch_bounds__(THREADS)
void pass_label(const f32x4* __restrict__ tgt,
                unsigned short* __restrict__ lab16,
                unsigned int* __restrict__ cnt_part,
                unsigned int* __restrict__ pb) {
    __shared__ unsigned int scnt[CC];
    const int tid = threadIdx.x;
    if (tid < CC) scnt[tid] = 0u;
    __syncthreads();

    const int b   = blockIdx.x / BLOCKS_PER_SAMPLE;
    const int blk = blockIdx.x % BLOCKS_PER_SAMPLE;
    const int S4  = SS / 4;
    const f32x4* base = tgt + (size_t)b * CC * S4;
    unsigned short* lab = lab16 + (size_t)b * S4;

    for (int it = 0; it < GPT; ++it) {
        const int g = blk * (THREADS * GPT) + it * THREADS + tid;
        f32x4 v[CC];
        #pragma unroll
        for (int c = 0; c < CC; ++c) v[c] = __builtin_nontemporal_load(base + (size_t)c * S4 + g);

        int l0 = 0, l1 = 0, l2 = 0, l3 = 0;
        #pragma unroll
        for (int c = 1; c < CC; ++c) {
            if (v[c][0] > 0.5f) l0 = c;
            if (v[c][1] > 0.5f) l1 = c;
            if (v[c][2] > 0.5f) l2 = c;
            if (v[c][3] > 0.5f) l3 = c;
        }
        lab[g] = (unsigned short)(l0 | (l1 << 4) | (l2 << 8) | (l3 << 12));
        atomicAdd(&scnt[l0], 1u);   // LDS atomics: no cross-block contention
        atomicAdd(&scnt[l1], 1u);
        atomicAdd(&scnt[l2], 1u);
        atomicAdd(&scnt[l3], 1u);
    }
    __syncthreads();
    if (tid < CC) cnt_part[tid * NBLOCKS + blockIdx.x] = scnt[tid];
    if (tid == 0) {
        unsigned int mask = 0;
        #pragma unroll
        for (int c = 0; c < CC; ++c) mask |= (scnt[c] > 0u) ? (1u << c) : 0u;
        pb[blockIdx.x] = mask;
    }
}

// Kernel 2: wave-0-only pb OR-reduce (6.4 KB, coalesced, shuffle tree — no
// extra VGPR pressure on the main loop), then R5's streaming main loop:
// net_output (nontemporal) + packed labels -> per-block partials.
__global__ __launch_bounds__(THREADS)
void pass_main(const f32x4* __restrict__ net,
               const unsigned short* __restrict__ lab16,
               const unsigned int* __restrict__ pb,
               float* __restrict__ part) {
    __shared__ unsigned int smask[2];
    __shared__ float s_red[2 * CC + 1];   // seg[8], inter[8], ce

    const int tid = threadIdx.x;
    const int b   = blockIdx.x / BLOCKS_PER_SAMPLE;
    const int blk = blockIdx.x % BLOCKS_PER_SAMPLE;

    if (tid < 64) {
        unsigned int om0 = 0, om1 = 0;
        #pragma unroll
        for (int k = 0; k < NBLOCKS / 64; ++k) {    // 25 coalesced loads/lane
            const int idx = tid + (k << 6);
            const unsigned int m = pb[idx];
            if (idx < BLOCKS_PER_SAMPLE) om0 |= m; else om1 |= m;
        }
        #pragma unroll
        for (int off = 32; off > 0; off >>= 1) {
            om0 |= __shfl_down(om0, off, 64);
            om1 |= __shfl_down(om1, off, 64);
        }
        if (tid == 0) { smask[0] = om0; smask[1] = om1; }
    }
    if (tid < 2 * CC + 1) s_red[tid] = 0.0f;
    __syncthreads();

    const unsigned int mask0 = smask[0], mask1 = smask[1];
    const int n0 = __popc(mask0), n1 = __popc(mask1);
    const int maxn = n0 > n1 ? n0 : n1;
    const float padf = (float)(maxn - ((b == 0) ? n0 : n1));
    const unsigned int maskb = (b == 0) ? mask0 : mask1;
    float ab[CC], bias[CC];
    #pragma unroll
    for (int c = 0; c < CC; ++c) {
        ab[c]   = ((maskb >> c) & 1u) ? 0.0f : 1.0f;
        bias[c] = -2048.0f * ab[c];
    }

    float segA[CC];
    float intA[CC];
    #pragma unroll
    for (int c = 0; c < CC; ++c) { segA[c] = 0.0f; intA[c] = 0.0f; }
    float ceA = 0.0f;

    const int S4 = SS / 4;
    const f32x4* base = net + (size_t)b * CC * S4;
    const unsigned short* lab = lab16 + (size_t)b * S4;

    for (int it = 0; it < GPT; ++it) {
        const int g = blk * (THREADS * GPT) + it * THREADS + tid;
        f32x4 v[CC];
        #pragma unroll
        for (int c = 0; c < CC; ++c) v[c] = __builtin_nontemporal_load(base + (size_t)c * S4 + g);
        const unsigned int Lp = lab[g];

        #pragma unroll
        for (int j = 0; j < 4; ++j) {
            const int lab_j = (Lp >> (4 * j)) & 0xF;
            float m[CC];
            m[0] = v[0][j];
            // absent-foreground fold, explicit pairwise tree (no fast-math reassoc)
            float f1 = ab[1] * v[1][j];
            float f2 = ab[2] * v[2][j];
            float f3 = ab[3] * v[3][j];
            float f4 = ab[4] * v[4][j];
            float f5 = ab[5] * v[5][j];
            float f6 = ab[6] * v[6][j];
            float f7 = ab[7] * v[7][j];
            #pragma unroll
            for (int c = 1; c < CC; ++c) m[c] = v[c][j];
            m[0] += ((f1 + f2) + (f3 + f4)) + ((f5 + f6) + f7);

            // e[c] = present ? exp(m[c]) : 0   (bias -2048 underflows exp2 to 0)
            float e[CC];
            #pragma unroll
            for (int c = 0; c < CC; ++c)
                e[c] = __builtin_amdgcn_exp2f(fmaf(m[c], L2E, bias[c]));
            const float sp = ((e[0] + e[1]) + (e[2] + e[3])) + ((e[4] + e[5]) + (e[6] + e[7]));
            const float se = sp + padf;         // zero-logit padding: exp(0)*pad
            const float lse = LN2 * __builtin_amdgcn_logf(se);

            float inv = __builtin_amdgcn_rcpf(sp);
            inv = inv * (2.0f - sp * inv);      // 1 Newton step

            float mlab = 0.0f;
            #pragma unroll
            for (int c = 0; c < CC; ++c) {
                const float p = e[c] * inv;
                segA[c] += p;
                const bool isl = (lab_j == c);
                intA[c] += isl ? p : 0.0f;
                mlab     = isl ? m[c] : mlab;
            }
            ceA += lse - mlab;
        }
    }

    // wave-level reduction (64 lanes) then LDS accumulation
    #pragma unroll
    for (int off = 32; off > 0; off >>= 1) {
        #pragma unroll
        for (int c = 0; c < CC; ++c) {
            segA[c] += __shfl_down(segA[c], off, 64);
            intA[c] += __shfl_down(intA[c], off, 64);
        }
        ceA += __shfl_down(ceA, off, 64);
    }
    if ((tid & 63) == 0) {
        #pragma unroll
        for (int c = 0; c < CC; ++c) {
            atomicAdd(&s_red[c],      segA[c]);
            atomicAdd(&s_red[CC + c], intA[c]);
        }
        atomicAdd(&s_red[2 * CC], ceA);
    }
    __syncthreads();
    if (tid < 2 * CC + 1) part[tid * NBLOCKS + blockIdx.x] = s_red[tid];
}

// Kernel 3: reduce per-block fp partials + count partials, write scalar loss.
__global__ __launch_bounds__(512)
void finalize(const unsigned int* __restrict__ cnt_part,
              const float* __restrict__ part,
              float* __restrict__ out) {
    __shared__ float sred[2 * CC + 1][2];
    __shared__ unsigned int sc[2 * CC];
    const int tid = threadIdx.x;
    const int w = tid >> 6, lane = tid & 63;

    // fp partials: wave w handles columns q = w, w+8, w+16
    for (int q = w; q < 2 * CC + 1; q += 8) {
        float a0 = 0.0f, a1 = 0.0f;
        const float* col = part + q * NBLOCKS;
        #pragma unroll
        for (int k = 0; k < NBLOCKS / 64; ++k) {
            const int idx = lane + (k << 6);
            const float v = col[idx];
            if (idx < BLOCKS_PER_SAMPLE) a0 += v; else a1 += v;
        }
        #pragma unroll
        for (int off = 32; off > 0; off >>= 1) {
            a0 += __shfl_down(a0, off, 64);
            a1 += __shfl_down(a1, off, 64);
        }
        if (lane == 0) { sred[q][0] = a0; sred[q][1] = a1; }
    }
    // count partials: wave w handles channel w
    {
        unsigned int a0 = 0, a1 = 0;
        const unsigned int* col = cnt_part + w * NBLOCKS;
        #pragma unroll
        for (int k = 0; k < NBLOCKS / 64; ++k) {
            const int idx = lane + (k << 6);
            const unsigned int v = col[idx];
            if (idx < BLOCKS_PER_SAMPLE) a0 += v; else a1 += v;
        }
        #pragma unroll
        for (int off = 32; off > 0; off >>= 1) {
            a0 += __shfl_down(a0, off, 64);
            a1 += __shfl_down(a1, off, 64);
        }
        if (lane == 0) { sc[w] = a0; sc[CC + w] = a1; }
    }
    __syncthreads();
    if (tid == 0) {
        const float ce = (sred[2 * CC][0] + sred[2 * CC][1]) / (float)NVOX;
        float dc = 0.0f;
        for (int b = 0; b < BB; ++b) {
            int nb = 0;
            float acc = 0.0f;
            for (int c = 0; c < CC; ++c) {
                const unsigned int cnt = sc[b * CC + c];
                if (cnt > 0u) {
                    ++nb;
                    const float R = (float)cnt;
                    const float Sg = sred[c][b];
                    const float I  = sred[CC + c][b];
                    acc += 2.0f * I / (R + Sg + 1e-5f);
                }
            }
            dc += 1.0f - acc / (float)nb;
        }
        dc /= (float)BB;
        out[0] = 0.5f * ce + 0.5f * dc;
    }
}

extern "C" void kernel_launch(void* const* d_in, const int* in_sizes, int n_in,
                              void* d_out, int out_size, void* d_ws, size_t ws_size,
                              hipStream_t stream) {
    const f32x4* net = (const f32x4*)d_in[0];
    const f32x4* tgt = (const f32x4*)d_in[1];
    float* out = (float*)d_out;

    // workspace layout (every slot fully rewritten by its producer each call)
    unsigned int*   cnt_part = (unsigned int*)d_ws;                      // 8*1600 u32  @0       (51200 B)
    unsigned int*   pb       = (unsigned int*)((char*)d_ws + 51200);     // 1600 u32    @51200   (6400 B)
    float*          part     = (float*)((char*)d_ws + 57600);            // 17*1600 f32 @57600   (108800 B)
    unsigned short* lab16    = (unsigned short*)((char*)d_ws + 166400);  // NVOX/4 ushort (1.64 MB)

    pass_label<<<NBLOCKS, THREADS, 0, stream>>>(tgt, lab16, cnt_part, pb);
    pass_main<<<NBLOCKS, THREADS, 0, stream>>>(net, lab16, pb, part);
    finalize<<<1, 512, 0, stream>>>(cnt_part, part, out);
}

// Round 9
// 45.027 us; speedup vs baseline: 1.2531x; 1.0249x over previous
//
#include <hip/hip_runtime.h>
#include <math.h>

// Problem constants (from reference)
#define BB 2
#define CC 8
#define DD 64
#define HH 160
#define WW 160
#define SS (DD*HH*WW)            // 1,638,400 voxels per sample per channel
#define NVOX (BB*SS)             // 3,276,800 total voxels
#define THREADS 256
#define GPT 2                    // float4 groups per thread
#define BLOCKS_PER_SAMPLE (SS/(THREADS*4*GPT))   // 800
#define NBLOCKS (BB*BLOCKS_PER_SAMPLE)           // 1600

#define L2E 1.4426950408889634f
#define LN2 0.6931471805599453f

typedef float f32x4 __attribute__((ext_vector_type(4)));

// Kernel 1: read target (one-hot, nontemporal), write packed 4-bit labels
// (ushort per float4-group), per-block count partials + per-block presence
// bitmask pb[block] (plain stores, no contention).
__global__ __launch_bounds__(THREADS)
void pass_label(const f32x4* __restrict__ tgt,
                unsigned short* __restrict__ lab16,
                unsigned int* __restrict__ cnt_part,
                unsigned int* __restrict__ pb) {
    __shared__ unsigned int scnt[CC];
    const int tid = threadIdx.x;
    if (tid < CC) scnt[tid] = 0u;
    __syncthreads();

    const int b   = blockIdx.x / BLOCKS_PER_SAMPLE;
    const int blk = blockIdx.x % BLOCKS_PER_SAMPLE;
    const int S4  = SS / 4;
    const f32x4* base = tgt + (size_t)b * CC * S4;
    unsigned short* lab = lab16 + (size_t)b * S4;

    for (int it = 0; it < GPT; ++it) {
        const int g = blk * (THREADS * GPT) + it * THREADS + tid;
        f32x4 v[CC];
        #pragma unroll
        for (int c = 0; c < CC; ++c) v[c] = __builtin_nontemporal_load(base + (size_t)c * S4 + g);

        int l0 = 0, l1 = 0, l2 = 0, l3 = 0;
        #pragma unroll
        for (int c = 1; c < CC; ++c) {
            if (v[c][0] > 0.5f) l0 = c;
            if (v[c][1] > 0.5f) l1 = c;
            if (v[c][2] > 0.5f) l2 = c;
            if (v[c][3] > 0.5f) l3 = c;
        }
        lab[g] = (unsigned short)(l0 | (l1 << 4) | (l2 << 8) | (l3 << 12));
        atomicAdd(&scnt[l0], 1u);   // LDS atomics: no cross-block contention
        atomicAdd(&scnt[l1], 1u);
        atomicAdd(&scnt[l2], 1u);
        atomicAdd(&scnt[l3], 1u);
    }
    __syncthreads();
    if (tid < CC) cnt_part[tid * NBLOCKS + blockIdx.x] = scnt[tid];
    if (tid == 0) {
        unsigned int mask = 0;
        #pragma unroll
        for (int c = 0; c < CC; ++c) mask |= (scnt[c] > 0u) ? (1u << c) : 0u;
        pb[blockIdx.x] = mask;
    }
}

// Kernel 2: wave-0-only pb OR-reduce (6.4 KB, coalesced, shuffle tree), then
// streaming main loop: net_output (nontemporal) + packed labels ->
// per-block partials for seg[8], inter[8], ce.
__global__ __launch_bounds__(THREADS)
void pass_main(const f32x4* __restrict__ net,
               const unsigned short* __restrict__ lab16,
               const unsigned int* __restrict__ pb,
               float* __restrict__ part) {
    __shared__ unsigned int smask[2];
    __shared__ float s_red[2 * CC + 1];   // seg[8], inter[8], ce

    const int tid = threadIdx.x;
    const int b   = blockIdx.x / BLOCKS_PER_SAMPLE;
    const int blk = blockIdx.x % BLOCKS_PER_SAMPLE;

    if (tid < 64) {
        unsigned int om0 = 0, om1 = 0;
        #pragma unroll
        for (int k = 0; k < NBLOCKS / 64; ++k) {    // 25 coalesced loads/lane
            const int idx = tid + (k << 6);
            const unsigned int m = pb[idx];
            om0 |= (idx < BLOCKS_PER_SAMPLE) ? m : 0u;
            om1 |= (idx < BLOCKS_PER_SAMPLE) ? 0u : m;
        }
        #pragma unroll
        for (int off = 32; off > 0; off >>= 1) {
            om0 |= __shfl_down(om0, off, 64);
            om1 |= __shfl_down(om1, off, 64);
        }
        if (tid == 0) { smask[0] = om0; smask[1] = om1; }
    }
    if (tid < 2 * CC + 1) s_red[tid] = 0.0f;
    __syncthreads();

    const unsigned int mask0 = smask[0], mask1 = smask[1];
    const int n0 = __popc(mask0), n1 = __popc(mask1);
    const int maxn = n0 > n1 ? n0 : n1;
    const float padf = (float)(maxn - ((b == 0) ? n0 : n1));
    const unsigned int maskb = (b == 0) ? mask0 : mask1;
    float ab[CC], bias[CC];
    #pragma unroll
    for (int c = 0; c < CC; ++c) {
        ab[c]   = ((maskb >> c) & 1u) ? 0.0f : 1.0f;
        bias[c] = -2048.0f * ab[c];
    }

    float segA[CC];
    float intA[CC];
    #pragma unroll
    for (int c = 0; c < CC; ++c) { segA[c] = 0.0f; intA[c] = 0.0f; }
    float ceA = 0.0f;

    const int S4 = SS / 4;
    const f32x4* base = net + (size_t)b * CC * S4;
    const unsigned short* lab = lab16 + (size_t)b * S4;

    for (int it = 0; it < GPT; ++it) {
        const int g = blk * (THREADS * GPT) + it * THREADS + tid;
        f32x4 v[CC];
        #pragma unroll
        for (int c = 0; c < CC; ++c) v[c] = __builtin_nontemporal_load(base + (size_t)c * S4 + g);
        const unsigned int Lp = lab[g];

        #pragma unroll
        for (int j = 0; j < 4; ++j) {
            const int lab_j = (Lp >> (4 * j)) & 0xF;
            float m[CC];
            m[0] = v[0][j];
            // absent-foreground fold, explicit pairwise tree (no fast-math reassoc)
            float f1 = ab[1] * v[1][j];
            float f2 = ab[2] * v[2][j];
            float f3 = ab[3] * v[3][j];
            float f4 = ab[4] * v[4][j];
            float f5 = ab[5] * v[5][j];
            float f6 = ab[6] * v[6][j];
            float f7 = ab[7] * v[7][j];
            #pragma unroll
            for (int c = 1; c < CC; ++c) m[c] = v[c][j];
            m[0] += ((f1 + f2) + (f3 + f4)) + ((f5 + f6) + f7);

            // e[c] = present ? exp(m[c]) : 0   (bias -2048 underflows exp2 to 0)
            float e[CC];
            #pragma unroll
            for (int c = 0; c < CC; ++c)
                e[c] = __builtin_amdgcn_exp2f(fmaf(m[c], L2E, bias[c]));
            const float sp = ((e[0] + e[1]) + (e[2] + e[3])) + ((e[4] + e[5]) + (e[6] + e[7]));
            const float se = sp + padf;         // zero-logit padding: exp(0)*pad
            const float lse = LN2 * __builtin_amdgcn_logf(se);

            const float inv = __builtin_amdgcn_rcpf(sp);  // ~2.5e-7 rel err, OK vs 3.3e-2 thr

            float mlab = 0.0f;
            #pragma unroll
            for (int c = 0; c < CC; ++c) {
                const float p = e[c] * inv;
                segA[c] += p;
                const bool isl = (lab_j == c);
                intA[c] += isl ? p : 0.0f;
                mlab     = isl ? m[c] : mlab;
            }
            ceA += lse - mlab;
        }
    }

    // wave-level reduction (64 lanes) then LDS accumulation
    #pragma unroll
    for (int off = 32; off > 0; off >>= 1) {
        #pragma unroll
        for (int c = 0; c < CC; ++c) {
            segA[c] += __shfl_down(segA[c], off, 64);
            intA[c] += __shfl_down(intA[c], off, 64);
        }
        ceA += __shfl_down(ceA, off, 64);
    }
    if ((tid & 63) == 0) {
        #pragma unroll
        for (int c = 0; c < CC; ++c) {
            atomicAdd(&s_red[c],      segA[c]);
            atomicAdd(&s_red[CC + c], intA[c]);
        }
        atomicAdd(&s_red[2 * CC], ceA);
    }
    __syncthreads();
    if (tid < 2 * CC + 1) part[tid * NBLOCKS + blockIdx.x] = s_red[tid];
}

// Kernel 3: reduce per-block fp partials + count partials, write scalar loss.
// 1024 threads = 16 waves: one wave per fp column (17th column handled by wave 0
// second pass), one wave per count channel.
__global__ __launch_bounds__(1024)
void finalize(const unsigned int* __restrict__ cnt_part,
              const float* __restrict__ part,
              float* __restrict__ out) {
    __shared__ float sred[2 * CC + 1][2];
    __shared__ unsigned int sc[2 * CC];
    const int tid = threadIdx.x;
    const int w = tid >> 6, lane = tid & 63;

    // fp partials: wave w handles columns q = w, w+16
    for (int q = w; q < 2 * CC + 1; q += 16) {
        float a0 = 0.0f, a1 = 0.0f;
        const float* col = part + q * NBLOCKS;
        #pragma unroll
        for (int k = 0; k < NBLOCKS / 64; ++k) {
            const int idx = lane + (k << 6);
            const float v = col[idx];
            if (idx < BLOCKS_PER_SAMPLE) a0 += v; else a1 += v;
        }
        #pragma unroll
        for (int off = 32; off > 0; off >>= 1) {
            a0 += __shfl_down(a0, off, 64);
            a1 += __shfl_down(a1, off, 64);
        }
        if (lane == 0) { sred[q][0] = a0; sred[q][1] = a1; }
    }
    // count partials: waves 0..7 handle channel w (redundant with fp loop waves, cheap)
    if (w < CC) {
        unsigned int a0 = 0, a1 = 0;
        const unsigned int* col = cnt_part + w * NBLOCKS;
        #pragma unroll
        for (int k = 0; k < NBLOCKS / 64; ++k) {
            const int idx = lane + (k << 6);
            const unsigned int v = col[idx];
            if (idx < BLOCKS_PER_SAMPLE) a0 += v; else a1 += v;
        }
        #pragma unroll
        for (int off = 32; off > 0; off >>= 1) {
            a0 += __shfl_down(a0, off, 64);
            a1 += __shfl_down(a1, off, 64);
        }
        if (lane == 0) { sc[w] = a0; sc[CC + w] = a1; }
    }
    __syncthreads();
    if (tid == 0) {
        const float ce = (sred[2 * CC][0] + sred[2 * CC][1]) / (float)NVOX;
        float dc = 0.0f;
        for (int b = 0; b < BB; ++b) {
            int nb = 0;
            float acc = 0.0f;
            for (int c = 0; c < CC; ++c) {
                const unsigned int cnt = sc[b * CC + c];
                if (cnt > 0u) {
                    ++nb;
                    const float R = (float)cnt;
                    const float Sg = sred[c][b];
                    const float I  = sred[CC + c][b];
                    acc += 2.0f * I / (R + Sg + 1e-5f);
                }
            }
            dc += 1.0f - acc / (float)nb;
        }
        dc /= (float)BB;
        out[0] = 0.5f * ce + 0.5f * dc;
    }
}

extern "C" void kernel_launch(void* const* d_in, const int* in_sizes, int n_in,
                              void* d_out, int out_size, void* d_ws, size_t ws_size,
                              hipStream_t stream) {
    const f32x4* net = (const f32x4*)d_in[0];
    const f32x4* tgt = (const f32x4*)d_in[1];
    float* out = (float*)d_out;

    // workspace layout (every slot fully rewritten by its producer each call)
    unsigned int*   cnt_part = (unsigned int*)d_ws;                      // 8*1600 u32  @0       (51200 B)
    unsigned int*   pb       = (unsigned int*)((char*)d_ws + 51200);     // 1600 u32    @51200   (6400 B)
    float*          part     = (float*)((char*)d_ws + 57600);            // 17*1600 f32 @57600   (108800 B)
    unsigned short* lab16    = (unsigned short*)((char*)d_ws + 166400);  // NVOX/4 ushort (1.64 MB)

    pass_label<<<NBLOCKS, THREADS, 0, stream>>>(tgt, lab16, cnt_part, pb);
    pass_main<<<NBLOCKS, THREADS, 0, stream>>>(net, lab16, pb, part);
    finalize<<<1, 1024, 0, stream>>>(cnt_part, part, out);
}